// Round 2
// baseline (353.378 us; speedup 1.0000x reference)
//
#include <hip/hip_runtime.h>
#include <float.h>
#include <math.h>

#define NBATCH   4096
#define NAGENT   16
#define NTASK    16
#define DDIM     128
#define G        8      // batches per block (one per wave)
#define NTHREADS 512    // 8 waves

// scratch swizzle: 4 segments of 64 dwords, segment stride 72 dwords
// -> the 4 iseg broadcast groups hit disjoint bank octets
__device__ __forceinline__ int swz(int i) { return (i & 63) + (i >> 6) * 72; }
#define SCR_STRIDE 288  // 4 * 72

__global__ __launch_bounds__(NTHREADS, 4)
void alloc_policy_kernel(const float* __restrict__ task_embeds,
                         const float* __restrict__ task_nonag,
                         const float* __restrict__ agent_embeds,
                         const unsigned char* __restrict__ task_mask,
                         const float* __restrict__ agent_mask,
                         const float* __restrict__ gumbels,
                         const float* __restrict__ W_count,
                         const float* __restrict__ b_count,
                         const float* __restrict__ W_upd,
                         const float* __restrict__ b_upd,
                         float* __restrict__ out)
{
    // LDS: 64K te + 9216B scratch + 1.5K sdots + misc ~= 75.3KB -> 2 blocks/CU
    __shared__ __align__(16) float te[G][NTASK][DDIM];
    __shared__ __align__(16) float scr[G][SCR_STRIDE];
    __shared__ float sdots[G][NAGENT][3];   // s0,s1,s2 per (g, a)
    __shared__ int   tstar_s[G];
    __shared__ float hsel_s[G];
    __shared__ float agm_s[G];

    const int tid  = threadIdx.x;
    const int lane = tid & 63;
    const int w    = tid >> 6;            // wave id == batch slot g
    const int b0   = blockIdx.x * G;
    const int gb_w = b0 + w;              // this wave's global batch

    // matvec mapping: col mj, i-segment iseg (4 segs x 64 i)
    const int mj   = tid >> 2;            // 0..127
    const int iseg = tid & 3;
    const float bu = b_upd[mj];

    const float scalef = sqrtf(128.0f);

    // ---- init te (block-wide coalesced copy)
    {
        const float4* src = (const float4*)(task_embeds + (size_t)b0 * NTASK * DDIM);
        float4* dst = (float4*)(&te[0][0][0]);
        #pragma unroll
        for (int k = 0; k < (G * NTASK * DDIM / 4) / NTHREADS; ++k)  // 8
            dst[k * NTHREADS + tid] = src[k * NTHREADS + tid];
    }

    // ---- init sdots: s0=dot(ag,Wc0), s1=dot(ag,Wc1), s2=dot(ag,bc) for 128 (g,a) pairs
    {
        const int p = tid >> 2, q = tid & 3;   // pair, quarter of D
        const int g = p >> 4,  a = p & 15;
        const float* agp = agent_embeds + ((size_t)(b0 + g) * NAGENT + a) * DDIM + q * 32;
        float a0 = 0.f, a1 = 0.f, a2 = 0.f;
        #pragma unroll
        for (int c = 0; c < 8; ++c) {
            const float4 av = *(const float4*)(agp + c * 4);
            const float4 w0 = *(const float4*)(W_count + q * 32 + c * 4);
            const float4 w1 = *(const float4*)(W_count + DDIM + q * 32 + c * 4);
            const float4 bc = *(const float4*)(b_count + q * 32 + c * 4);
            a0 = fmaf(av.x, w0.x, a0); a0 = fmaf(av.y, w0.y, a0);
            a0 = fmaf(av.z, w0.z, a0); a0 = fmaf(av.w, w0.w, a0);
            a1 = fmaf(av.x, w1.x, a1); a1 = fmaf(av.y, w1.y, a1);
            a1 = fmaf(av.z, w1.z, a1); a1 = fmaf(av.w, w1.w, a1);
            a2 = fmaf(av.x, bc.x, a2); a2 = fmaf(av.y, bc.y, a2);
            a2 = fmaf(av.z, bc.z, a2); a2 = fmaf(av.w, bc.w, a2);
        }
        a0 += __shfl_xor(a0, 1); a0 += __shfl_xor(a0, 2);
        a1 += __shfl_xor(a1, 1); a1 += __shfl_xor(a1, 2);
        a2 += __shfl_xor(a2, 1); a2 += __shfl_xor(a2, 2);
        if (q == 0) { sdots[g][a][0] = a0; sdots[g][a][1] = a1; sdots[g][a][2] = a2; }
    }

    // ---- per-lane task-slot constants: lane owns task tau (x4 replicas)
    const int tau = (lane >> 2) & 15;
    const float nn_my = task_nonag[gb_w * NTASK + tau];
    const unsigned char mask_my = task_mask[gb_w * NTASK + tau];
    float cc_my = 0.0f;

    __syncthreads();

    for (int a = 0; a < NAGENT; ++a) {
        // ================= phase L: wave-private (batch = w) =================
        const float2 ag2 = *(const float2*)(agent_embeds +
                             ((size_t)gb_w * NAGENT + a) * DDIM + lane * 2);

        // per-lane partials of dot(ag, te[t]) over this lane's 2 d-channels
        float v[16];
        #pragma unroll
        for (int t = 0; t < 16; ++t) {
            const float2 t2 = *(const float2*)(&te[w][t][lane * 2]);
            v[t] = fmaf(ag2.y, t2.y, ag2.x * t2.x);
        }
        // packed butterfly: 16 dots reduced across 64 lanes in 17 shfl
        {
            const bool h5 = (lane & 32) != 0;
            #pragma unroll
            for (int k = 0; k < 8; ++k) {
                const float send = h5 ? v[k] : v[k + 8];
                const float mine = h5 ? v[k + 8] : v[k];
                v[k] = mine + __shfl_xor(send, 32);
            }
            const bool h4 = (lane & 16) != 0;
            #pragma unroll
            for (int k = 0; k < 4; ++k) {
                const float send = h4 ? v[k] : v[k + 4];
                const float mine = h4 ? v[k + 4] : v[k];
                v[k] = mine + __shfl_xor(send, 16);
            }
            const bool h3 = (lane & 8) != 0;
            #pragma unroll
            for (int k = 0; k < 2; ++k) {
                const float send = h3 ? v[k] : v[k + 2];
                const float mine = h3 ? v[k + 2] : v[k];
                v[k] = mine + __shfl_xor(send, 8);
            }
            {
                const bool h2 = (lane & 4) != 0;
                const float send = h2 ? v[0] : v[1];
                const float mine = h2 ? v[1] : v[0];
                v[0] = mine + __shfl_xor(send, 4);
            }
            v[0] += __shfl_xor(v[0], 2);
            v[0] += __shfl_xor(v[0], 1);
        }
        // lane now holds full dot(ag, te[tau])
        const float s0 = sdots[w][a][0];
        const float s1 = sdots[w][a][1];
        const float s2 = sdots[w][a][2];
        const float dot_total = v[0] + fmaf(nn_my, s0, fmaf(cc_my, s1, s2));
        float z = dot_total / scalef;
        if (mask_my) z = -FLT_MAX;
        z = z + gumbels[((size_t)a * NBATCH + gb_w) * NTASK + tau];

        // softmax over 16 tasks (task index varies over lane bits 5..2)
        float m = z;
        m = fmaxf(m, __shfl_xor(m, 32));
        m = fmaxf(m, __shfl_xor(m, 16));
        m = fmaxf(m, __shfl_xor(m, 8));
        m = fmaxf(m, __shfl_xor(m, 4));
        const float e = expf(z - m);
        float ss = e;
        ss += __shfl_xor(ss, 32);
        ss += __shfl_xor(ss, 16);
        ss += __shfl_xor(ss, 8);
        ss += __shfl_xor(ss, 4);
        const float sft = e / ss;

        // argmax with first-index tie-break
        float bv = sft; int bi = tau;
        {
            float ov; int oi;
            ov = __shfl_xor(bv, 32); oi = __shfl_xor(bi, 32);
            if (ov > bv || (ov == bv && oi < bi)) { bv = ov; bi = oi; }
            ov = __shfl_xor(bv, 16); oi = __shfl_xor(bi, 16);
            if (ov > bv || (ov == bv && oi < bi)) { bv = ov; bi = oi; }
            ov = __shfl_xor(bv, 8);  oi = __shfl_xor(bi, 8);
            if (ov > bv || (ov == bv && oi < bi)) { bv = ov; bi = oi; }
            ov = __shfl_xor(bv, 4);  oi = __shfl_xor(bi, 4);
            if (ov > bv || (ov == bv && oi < bi)) { bv = ov; bi = oi; }
        }

        const float agm = 1.0f - agent_mask[(size_t)gb_w * NAGENT + a];
        const float onehot = (tau == bi) ? 1.0f : 0.0f;
        const float hh = ((onehot - sft) + sft) * agm;  // exact 0 / exact agm

        if ((lane & 3) == 0)
            out[((size_t)gb_w * NAGENT + a) * NTASK + tau] = hh;
        cc_my = cc_my + hh * 0.1f;
        if (tau == bi && (lane & 3) == 0) {
            tstar_s[w] = bi; hsel_s[w] = hh; agm_s[w] = agm;
        }

        // stage relu(concat(te[bi], ag)) into swizzled scratch (wave-private)
        {
            const float2 tsel = *(const float2*)(&te[w][bi][lane * 2]);
            float2 r0, r1;
            r0.x = fmaxf(tsel.x, 0.f); r0.y = fmaxf(tsel.y, 0.f);
            r1.x = fmaxf(ag2.x, 0.f);  r1.y = fmaxf(ag2.y, 0.f);
            *(float2*)(&scr[w][swz(lane * 2)])       = r0;
            *(float2*)(&scr[w][swz(128 + lane * 2)]) = r1;
        }
        __syncthreads();

        // ================= phase M: W-amortized matvec over all 8 g =========
        float acc[G];
        #pragma unroll
        for (int g = 0; g < G; ++g) acc[g] = 0.f;
        {
            const int i0 = iseg * 64;
            #pragma unroll
            for (int c = 0; c < 16; ++c) {
                const int ii = i0 + c * 4;
                const float w0 = W_upd[(size_t)(ii + 0) * DDIM + mj];
                const float w1 = W_upd[(size_t)(ii + 1) * DDIM + mj];
                const float w2 = W_upd[(size_t)(ii + 2) * DDIM + mj];
                const float w3 = W_upd[(size_t)(ii + 3) * DDIM + mj];
                const int sb = c * 4 + iseg * 72;   // swz(ii)
                #pragma unroll
                for (int g = 0; g < G; ++g) {
                    const float4 in4 = *(const float4*)(&scr[g][sb]);
                    acc[g] = fmaf(in4.x, w0, acc[g]);
                    acc[g] = fmaf(in4.y, w1, acc[g]);
                    acc[g] = fmaf(in4.z, w2, acc[g]);
                    acc[g] = fmaf(in4.w, w3, acc[g]);
                }
            }
        }
        // reduce across the 4 adjacent iseg lanes
        #pragma unroll
        for (int g = 0; g < G; ++g) {
            float s = acc[g];
            s = s + __shfl_xor(s, 1);
            s = s + __shfl_xor(s, 2);
            acc[g] = s;
        }
        // epilogue: lane with iseg handles g in {2*iseg, 2*iseg+1}
        #pragma unroll
        for (int k = 0; k < 2; ++k) {
            const int g = iseg * 2 + k;
            const float u = acc[g] + bu;
            const int ts = tstar_s[g];
            const float addv = (u * hsel_s[g]) * agm_s[g];
            te[g][ts][mj] += addv;
        }
        __syncthreads();
    }
}

extern "C" void kernel_launch(void* const* d_in, const int* in_sizes, int n_in,
                              void* d_out, int out_size, void* d_ws, size_t ws_size,
                              hipStream_t stream) {
    const float*         task_embeds  = (const float*)d_in[0];
    const float*         task_nonag   = (const float*)d_in[1];
    const float*         agent_embeds = (const float*)d_in[2];
    const unsigned char* task_mask    = (const unsigned char*)d_in[3];
    const float*         agent_mask   = (const float*)d_in[4];
    const float*         gumbels      = (const float*)d_in[5];
    const float*         W_count      = (const float*)d_in[6];
    const float*         b_count      = (const float*)d_in[7];
    const float*         W_upd        = (const float*)d_in[8];
    const float*         b_upd       = (const float*)d_in[9];
    float* out = (float*)d_out;

    dim3 grid(NBATCH / G);
    dim3 block(NTHREADS);
    hipLaunchKernelGGL(alloc_policy_kernel, grid, block, 0, stream,
                       task_embeds, task_nonag, agent_embeds, task_mask,
                       agent_mask, gumbels, W_count, b_count, W_upd, b_upd, out);
}

// Round 3
// 227.855 us; speedup vs baseline: 1.5509x; 1.5509x over previous
//
#include <hip/hip_runtime.h>
#include <float.h>
#include <math.h>

#define NBATCH   4096
#define NAGENT   16
#define NTASK    16
#define DDIM     128
#define G        8      // batches per block (one per wave)
#define NTHREADS 512    // 8 waves

// scratch swizzle: 4 segments of 64 dwords, segment stride 72 dwords
// -> the 4 iseg broadcast groups hit disjoint bank octets
__device__ __forceinline__ int swz(int i) { return (i & 63) + (i >> 6) * 72; }
#define SCR_STRIDE 288  // 4 * 72

// launch_bounds(512,2): LDS (76.8KB) caps us at 2 blocks/CU = 16 waves/CU anyway;
// (512,4) was interpreted as an 8-wave/SIMD occupancy target -> 64-VGPR cap ->
// massive scratch spills (922MB FETCH / 113MB WRITE in rocprof). Keep VGPR cap >= 128.
__global__ __launch_bounds__(NTHREADS, 2)
void alloc_policy_kernel(const float* __restrict__ task_embeds,
                         const float* __restrict__ task_nonag,
                         const float* __restrict__ agent_embeds,
                         const unsigned char* __restrict__ task_mask,
                         const float* __restrict__ agent_mask,
                         const float* __restrict__ gumbels,
                         const float* __restrict__ W_count,
                         const float* __restrict__ b_count,
                         const float* __restrict__ W_upd,
                         const float* __restrict__ b_upd,
                         float* __restrict__ out)
{
    // LDS: 64K te + 9216B scratch + 1.5K sdots + misc ~= 75.3KB -> 2 blocks/CU
    __shared__ __align__(16) float te[G][NTASK][DDIM];
    __shared__ __align__(16) float scr[G][SCR_STRIDE];
    __shared__ float sdots[G][NAGENT][3];   // s0,s1,s2 per (g, a)
    __shared__ int   tstar_s[G];
    __shared__ float hsel_s[G];
    __shared__ float agm_s[G];

    const int tid  = threadIdx.x;
    const int lane = tid & 63;
    const int w    = tid >> 6;            // wave id == batch slot g
    const int b0   = blockIdx.x * G;
    const int gb_w = b0 + w;              // this wave's global batch

    // matvec mapping: col mj, i-segment iseg (4 segs x 64 i)
    const int mj   = tid >> 2;            // 0..127
    const int iseg = tid & 3;
    const float bu = b_upd[mj];

    const float scalef = sqrtf(128.0f);

    // ---- init te (block-wide coalesced copy)
    {
        const float4* src = (const float4*)(task_embeds + (size_t)b0 * NTASK * DDIM);
        float4* dst = (float4*)(&te[0][0][0]);
        #pragma unroll
        for (int k = 0; k < (G * NTASK * DDIM / 4) / NTHREADS; ++k)  // 8
            dst[k * NTHREADS + tid] = src[k * NTHREADS + tid];
    }

    // ---- init sdots: s0=dot(ag,Wc0), s1=dot(ag,Wc1), s2=dot(ag,bc) for 128 (g,a) pairs
    {
        const int p = tid >> 2, q = tid & 3;   // pair, quarter of D
        const int g = p >> 4,  a = p & 15;
        const float* agp = agent_embeds + ((size_t)(b0 + g) * NAGENT + a) * DDIM + q * 32;
        float a0 = 0.f, a1 = 0.f, a2 = 0.f;
        #pragma unroll
        for (int c = 0; c < 8; ++c) {
            const float4 av = *(const float4*)(agp + c * 4);
            const float4 w0 = *(const float4*)(W_count + q * 32 + c * 4);
            const float4 w1 = *(const float4*)(W_count + DDIM + q * 32 + c * 4);
            const float4 bc = *(const float4*)(b_count + q * 32 + c * 4);
            a0 = fmaf(av.x, w0.x, a0); a0 = fmaf(av.y, w0.y, a0);
            a0 = fmaf(av.z, w0.z, a0); a0 = fmaf(av.w, w0.w, a0);
            a1 = fmaf(av.x, w1.x, a1); a1 = fmaf(av.y, w1.y, a1);
            a1 = fmaf(av.z, w1.z, a1); a1 = fmaf(av.w, w1.w, a1);
            a2 = fmaf(av.x, bc.x, a2); a2 = fmaf(av.y, bc.y, a2);
            a2 = fmaf(av.z, bc.z, a2); a2 = fmaf(av.w, bc.w, a2);
        }
        a0 += __shfl_xor(a0, 1); a0 += __shfl_xor(a0, 2);
        a1 += __shfl_xor(a1, 1); a1 += __shfl_xor(a1, 2);
        a2 += __shfl_xor(a2, 1); a2 += __shfl_xor(a2, 2);
        if (q == 0) { sdots[g][a][0] = a0; sdots[g][a][1] = a1; sdots[g][a][2] = a2; }
    }

    // ---- per-lane task-slot constants: lane owns task tau (x4 replicas)
    const int tau = (lane >> 2) & 15;
    const float nn_my = task_nonag[gb_w * NTASK + tau];
    const unsigned char mask_my = task_mask[gb_w * NTASK + tau];
    float cc_my = 0.0f;

    __syncthreads();

    for (int a = 0; a < NAGENT; ++a) {
        // ================= phase L: wave-private (batch = w) =================
        const float2 ag2 = *(const float2*)(agent_embeds +
                             ((size_t)gb_w * NAGENT + a) * DDIM + lane * 2);

        // per-lane partials of dot(ag, te[t]) over this lane's 2 d-channels
        float v[16];
        #pragma unroll
        for (int t = 0; t < 16; ++t) {
            const float2 t2 = *(const float2*)(&te[w][t][lane * 2]);
            v[t] = fmaf(ag2.y, t2.y, ag2.x * t2.x);
        }
        // packed butterfly: 16 dots reduced across 64 lanes in 17 shfl
        {
            const bool h5 = (lane & 32) != 0;
            #pragma unroll
            for (int k = 0; k < 8; ++k) {
                const float send = h5 ? v[k] : v[k + 8];
                const float mine = h5 ? v[k + 8] : v[k];
                v[k] = mine + __shfl_xor(send, 32);
            }
            const bool h4 = (lane & 16) != 0;
            #pragma unroll
            for (int k = 0; k < 4; ++k) {
                const float send = h4 ? v[k] : v[k + 4];
                const float mine = h4 ? v[k + 4] : v[k];
                v[k] = mine + __shfl_xor(send, 16);
            }
            const bool h3 = (lane & 8) != 0;
            #pragma unroll
            for (int k = 0; k < 2; ++k) {
                const float send = h3 ? v[k] : v[k + 2];
                const float mine = h3 ? v[k + 2] : v[k];
                v[k] = mine + __shfl_xor(send, 8);
            }
            {
                const bool h2 = (lane & 4) != 0;
                const float send = h2 ? v[0] : v[1];
                const float mine = h2 ? v[1] : v[0];
                v[0] = mine + __shfl_xor(send, 4);
            }
            v[0] += __shfl_xor(v[0], 2);
            v[0] += __shfl_xor(v[0], 1);
        }
        // lane now holds full dot(ag, te[tau])
        const float s0 = sdots[w][a][0];
        const float s1 = sdots[w][a][1];
        const float s2 = sdots[w][a][2];
        const float dot_total = v[0] + fmaf(nn_my, s0, fmaf(cc_my, s1, s2));
        float z = dot_total / scalef;
        if (mask_my) z = -FLT_MAX;
        z = z + gumbels[((size_t)a * NBATCH + gb_w) * NTASK + tau];

        // softmax over 16 tasks (task index varies over lane bits 5..2)
        float m = z;
        m = fmaxf(m, __shfl_xor(m, 32));
        m = fmaxf(m, __shfl_xor(m, 16));
        m = fmaxf(m, __shfl_xor(m, 8));
        m = fmaxf(m, __shfl_xor(m, 4));
        const float e = expf(z - m);
        float ss = e;
        ss += __shfl_xor(ss, 32);
        ss += __shfl_xor(ss, 16);
        ss += __shfl_xor(ss, 8);
        ss += __shfl_xor(ss, 4);
        const float sft = e / ss;

        // argmax with first-index tie-break
        float bv = sft; int bi = tau;
        {
            float ov; int oi;
            ov = __shfl_xor(bv, 32); oi = __shfl_xor(bi, 32);
            if (ov > bv || (ov == bv && oi < bi)) { bv = ov; bi = oi; }
            ov = __shfl_xor(bv, 16); oi = __shfl_xor(bi, 16);
            if (ov > bv || (ov == bv && oi < bi)) { bv = ov; bi = oi; }
            ov = __shfl_xor(bv, 8);  oi = __shfl_xor(bi, 8);
            if (ov > bv || (ov == bv && oi < bi)) { bv = ov; bi = oi; }
            ov = __shfl_xor(bv, 4);  oi = __shfl_xor(bi, 4);
            if (ov > bv || (ov == bv && oi < bi)) { bv = ov; bi = oi; }
        }

        const float agm = 1.0f - agent_mask[(size_t)gb_w * NAGENT + a];
        const float onehot = (tau == bi) ? 1.0f : 0.0f;
        const float hh = ((onehot - sft) + sft) * agm;  // exact 0 / exact agm

        if ((lane & 3) == 0)
            out[((size_t)gb_w * NAGENT + a) * NTASK + tau] = hh;
        cc_my = cc_my + hh * 0.1f;
        if (tau == bi && (lane & 3) == 0) {
            tstar_s[w] = bi; hsel_s[w] = hh; agm_s[w] = agm;
        }

        // stage relu(concat(te[bi], ag)) into swizzled scratch (wave-private)
        {
            const float2 tsel = *(const float2*)(&te[w][bi][lane * 2]);
            float2 r0, r1;
            r0.x = fmaxf(tsel.x, 0.f); r0.y = fmaxf(tsel.y, 0.f);
            r1.x = fmaxf(ag2.x, 0.f);  r1.y = fmaxf(ag2.y, 0.f);
            *(float2*)(&scr[w][swz(lane * 2)])       = r0;
            *(float2*)(&scr[w][swz(128 + lane * 2)]) = r1;
        }
        __syncthreads();

        // ================= phase M: W-amortized matvec over all 8 g =========
        float acc[G];
        #pragma unroll
        for (int g = 0; g < G; ++g) acc[g] = 0.f;
        {
            const int i0 = iseg * 64;
            #pragma unroll
            for (int c = 0; c < 16; ++c) {
                const int ii = i0 + c * 4;
                const float w0 = W_upd[(size_t)(ii + 0) * DDIM + mj];
                const float w1 = W_upd[(size_t)(ii + 1) * DDIM + mj];
                const float w2 = W_upd[(size_t)(ii + 2) * DDIM + mj];
                const float w3 = W_upd[(size_t)(ii + 3) * DDIM + mj];
                const int sb = c * 4 + iseg * 72;   // swz(ii)
                #pragma unroll
                for (int g = 0; g < G; ++g) {
                    const float4 in4 = *(const float4*)(&scr[g][sb]);
                    acc[g] = fmaf(in4.x, w0, acc[g]);
                    acc[g] = fmaf(in4.y, w1, acc[g]);
                    acc[g] = fmaf(in4.z, w2, acc[g]);
                    acc[g] = fmaf(in4.w, w3, acc[g]);
                }
            }
        }
        // reduce across the 4 adjacent iseg lanes
        #pragma unroll
        for (int g = 0; g < G; ++g) {
            float s = acc[g];
            s = s + __shfl_xor(s, 1);
            s = s + __shfl_xor(s, 2);
            acc[g] = s;
        }
        // epilogue: lane with iseg handles g in {2*iseg, 2*iseg+1}
        #pragma unroll
        for (int k = 0; k < 2; ++k) {
            const int g = iseg * 2 + k;
            const float u = acc[g] + bu;
            const int ts = tstar_s[g];
            const float addv = (u * hsel_s[g]) * agm_s[g];
            te[g][ts][mj] += addv;
        }
        __syncthreads();
    }
}

extern "C" void kernel_launch(void* const* d_in, const int* in_sizes, int n_in,
                              void* d_out, int out_size, void* d_ws, size_t ws_size,
                              hipStream_t stream) {
    const float*         task_embeds  = (const float*)d_in[0];
    const float*         task_nonag   = (const float*)d_in[1];
    const float*         agent_embeds = (const float*)d_in[2];
    const unsigned char* task_mask    = (const unsigned char*)d_in[3];
    const float*         agent_mask   = (const float*)d_in[4];
    const float*         gumbels      = (const float*)d_in[5];
    const float*         W_count      = (const float*)d_in[6];
    const float*         b_count      = (const float*)d_in[7];
    const float*         W_upd        = (const float*)d_in[8];
    const float*         b_upd        = (const float*)d_in[9];
    float* out = (float*)d_out;

    dim3 grid(NBATCH / G);
    dim3 block(NTHREADS);
    hipLaunchKernelGGL(alloc_policy_kernel, grid, block, 0, stream,
                       task_embeds, task_nonag, agent_embeds, task_mask,
                       agent_mask, gumbels, W_count, b_count, W_upd, b_upd, out);
}

// Round 4
// 219.410 us; speedup vs baseline: 1.6106x; 1.0385x over previous
//
#include <hip/hip_runtime.h>
#include <float.h>
#include <math.h>

#define NBATCH   4096
#define NAGENT   16
#define NTASK    16
#define DDIM     128
#define G        8      // batches per block (one per wave)
#define NTHREADS 512    // 8 waves

// scratch swizzle: 4 segments of 64 dwords, segment stride 72 dwords
// -> the 4 iseg broadcast groups hit disjoint bank octets
__device__ __forceinline__ int swz(int i) { return (i & 63) + (i >> 6) * 72; }
#define SCR_STRIDE 288  // 4 * 72

// (512,2): VGPR cap 256. (512,4) previously produced a 64-VGPR cap -> 1GB of
// scratch spills. LDS 75KB; observed residency 1 block/CU regardless, so we
// optimize for stall-freedom at 2 waves/SIMD instead of chasing occupancy.
__global__ __launch_bounds__(NTHREADS, 2)
void alloc_policy_kernel(const float* __restrict__ task_embeds,
                         const float* __restrict__ task_nonag,
                         const float* __restrict__ agent_embeds,
                         const unsigned char* __restrict__ task_mask,
                         const float* __restrict__ agent_mask,
                         const float* __restrict__ gumbels,
                         const float* __restrict__ W_count,
                         const float* __restrict__ b_count,
                         const float* __restrict__ W_upd,
                         const float* __restrict__ b_upd,
                         float* __restrict__ out)
{
    __shared__ __align__(16) float te[G][NTASK][DDIM];
    __shared__ __align__(16) float scr[G][SCR_STRIDE];
    __shared__ float sdots[G][NAGENT][3];   // s0,s1,s2 per (g, a)
    __shared__ int   tstar_s[G];
    __shared__ float hsel_s[G];
    __shared__ float agm_s[G];

    const int tid  = threadIdx.x;
    const int lane = tid & 63;
    const int w    = tid >> 6;            // wave id == batch slot g
    const int b0   = blockIdx.x * G;
    const int gb_w = b0 + w;              // this wave's global batch

    // matvec mapping: col mj, i-segment iseg (4 segs x 64 i)
    const int mj   = tid >> 2;            // 0..127
    const int iseg = tid & 3;
    const float bu = b_upd[mj];

    const float scalef = sqrtf(128.0f);

    // ---- W_upd slice -> registers, once. Wreg[c] = W_upd[iseg*64+c][mj].
    float Wreg[64];
    {
        const float* wp = W_upd + (size_t)(iseg * 64) * DDIM + mj;
        #pragma unroll
        for (int c = 0; c < 64; ++c)
            Wreg[c] = wp[(size_t)c * DDIM];
    }

    // ---- init te (block-wide coalesced copy)
    {
        const float4* src = (const float4*)(task_embeds + (size_t)b0 * NTASK * DDIM);
        float4* dst = (float4*)(&te[0][0][0]);
        #pragma unroll
        for (int k = 0; k < (G * NTASK * DDIM / 4) / NTHREADS; ++k)  // 8
            dst[k * NTHREADS + tid] = src[k * NTHREADS + tid];
    }

    // ---- init sdots: s0=dot(ag,Wc0), s1=dot(ag,Wc1), s2=dot(ag,bc) per (g,a)
    {
        const int p = tid >> 2, q = tid & 3;   // pair, quarter of D
        const int g = p >> 4,  a = p & 15;
        const float* agp = agent_embeds + ((size_t)(b0 + g) * NAGENT + a) * DDIM + q * 32;
        float a0 = 0.f, a1 = 0.f, a2 = 0.f;
        #pragma unroll
        for (int c = 0; c < 8; ++c) {
            const float4 av = *(const float4*)(agp + c * 4);
            const float4 w0 = *(const float4*)(W_count + q * 32 + c * 4);
            const float4 w1 = *(const float4*)(W_count + DDIM + q * 32 + c * 4);
            const float4 bc = *(const float4*)(b_count + q * 32 + c * 4);
            a0 = fmaf(av.x, w0.x, a0); a0 = fmaf(av.y, w0.y, a0);
            a0 = fmaf(av.z, w0.z, a0); a0 = fmaf(av.w, w0.w, a0);
            a1 = fmaf(av.x, w1.x, a1); a1 = fmaf(av.y, w1.y, a1);
            a1 = fmaf(av.z, w1.z, a1); a1 = fmaf(av.w, w1.w, a1);
            a2 = fmaf(av.x, bc.x, a2); a2 = fmaf(av.y, bc.y, a2);
            a2 = fmaf(av.z, bc.z, a2); a2 = fmaf(av.w, bc.w, a2);
        }
        a0 += __shfl_xor(a0, 1); a0 += __shfl_xor(a0, 2);
        a1 += __shfl_xor(a1, 1); a1 += __shfl_xor(a1, 2);
        a2 += __shfl_xor(a2, 1); a2 += __shfl_xor(a2, 2);
        if (q == 0) { sdots[g][a][0] = a0; sdots[g][a][1] = a1; sdots[g][a][2] = a2; }
    }

    // ---- per-lane task-slot constants: lane owns task tau (x4 replicas)
    const int tau = (lane >> 2) & 15;
    const float nn_my = task_nonag[gb_w * NTASK + tau];
    const unsigned char mask_my = task_mask[gb_w * NTASK + tau];
    float cc_my = 0.0f;

    // ---- prefetch step-0 per-step globals
    const float* agbase = agent_embeds + (size_t)gb_w * NAGENT * DDIM;
    float2 ag2 = *(const float2*)(agbase + lane * 2);                 // a=0
    float  gum = gumbels[((size_t)0 * NBATCH + gb_w) * NTASK + tau];  // a=0
    float  amk = agent_mask[(size_t)gb_w * NAGENT + 0];               // a=0

    __syncthreads();

    for (int a = 0; a < NAGENT; ++a) {
        // ================= phase L: wave-private (batch = w) =================
        // per-lane partials of dot(ag, te[t]) over this lane's 2 d-channels
        float v[16];
        #pragma unroll
        for (int t = 0; t < 16; ++t) {
            const float2 t2 = *(const float2*)(&te[w][t][lane * 2]);
            v[t] = fmaf(ag2.y, t2.y, ag2.x * t2.x);
        }
        // packed butterfly: 16 dots reduced across 64 lanes in 17 shfl
        {
            const bool h5 = (lane & 32) != 0;
            #pragma unroll
            for (int k = 0; k < 8; ++k) {
                const float send = h5 ? v[k] : v[k + 8];
                const float mine = h5 ? v[k + 8] : v[k];
                v[k] = mine + __shfl_xor(send, 32);
            }
            const bool h4 = (lane & 16) != 0;
            #pragma unroll
            for (int k = 0; k < 4; ++k) {
                const float send = h4 ? v[k] : v[k + 4];
                const float mine = h4 ? v[k + 4] : v[k];
                v[k] = mine + __shfl_xor(send, 16);
            }
            const bool h3 = (lane & 8) != 0;
            #pragma unroll
            for (int k = 0; k < 2; ++k) {
                const float send = h3 ? v[k] : v[k + 2];
                const float mine = h3 ? v[k + 2] : v[k];
                v[k] = mine + __shfl_xor(send, 8);
            }
            {
                const bool h2 = (lane & 4) != 0;
                const float send = h2 ? v[0] : v[1];
                const float mine = h2 ? v[1] : v[0];
                v[0] = mine + __shfl_xor(send, 4);
            }
            v[0] += __shfl_xor(v[0], 2);
            v[0] += __shfl_xor(v[0], 1);
        }
        // lane now holds full dot(ag, te[tau])
        const float s0 = sdots[w][a][0];
        const float s1 = sdots[w][a][1];
        const float s2 = sdots[w][a][2];
        const float dot_total = v[0] + fmaf(nn_my, s0, fmaf(cc_my, s1, s2));
        float z = dot_total / scalef;
        if (mask_my) z = -FLT_MAX;
        z = z + gum;

        // softmax over 16 tasks (task index varies over lane bits 5..2)
        float m = z;
        m = fmaxf(m, __shfl_xor(m, 32));
        m = fmaxf(m, __shfl_xor(m, 16));
        m = fmaxf(m, __shfl_xor(m, 8));
        m = fmaxf(m, __shfl_xor(m, 4));
        const float e = expf(z - m);
        float ss = e;
        ss += __shfl_xor(ss, 32);
        ss += __shfl_xor(ss, 16);
        ss += __shfl_xor(ss, 8);
        ss += __shfl_xor(ss, 4);
        const float sft = e / ss;

        // argmax with first-index tie-break
        float bv = sft; int bi = tau;
        {
            float ov; int oi;
            ov = __shfl_xor(bv, 32); oi = __shfl_xor(bi, 32);
            if (ov > bv || (ov == bv && oi < bi)) { bv = ov; bi = oi; }
            ov = __shfl_xor(bv, 16); oi = __shfl_xor(bi, 16);
            if (ov > bv || (ov == bv && oi < bi)) { bv = ov; bi = oi; }
            ov = __shfl_xor(bv, 8);  oi = __shfl_xor(bi, 8);
            if (ov > bv || (ov == bv && oi < bi)) { bv = ov; bi = oi; }
            ov = __shfl_xor(bv, 4);  oi = __shfl_xor(bi, 4);
            if (ov > bv || (ov == bv && oi < bi)) { bv = ov; bi = oi; }
        }

        const float agm = 1.0f - amk;
        const float onehot = (tau == bi) ? 1.0f : 0.0f;
        const float hh = ((onehot - sft) + sft) * agm;  // exact 0 / exact agm

        if ((lane & 3) == 0)
            out[((size_t)gb_w * NAGENT + a) * NTASK + tau] = hh;
        cc_my = cc_my + hh * 0.1f;
        if (tau == bi && (lane & 3) == 0) {
            tstar_s[w] = bi; hsel_s[w] = hh; agm_s[w] = agm;
        }

        // stage relu(concat(te[bi], ag)) into swizzled scratch (wave-private)
        {
            const float2 tsel = *(const float2*)(&te[w][bi][lane * 2]);
            float2 r0, r1;
            r0.x = fmaxf(tsel.x, 0.f); r0.y = fmaxf(tsel.y, 0.f);
            r1.x = fmaxf(ag2.x, 0.f);  r1.y = fmaxf(ag2.y, 0.f);
            *(float2*)(&scr[w][swz(lane * 2)])       = r0;
            *(float2*)(&scr[w][swz(128 + lane * 2)]) = r1;
        }
        __syncthreads();

        // ---- prefetch next step's globals (covered by the matvec below)
        const int an = (a + 1) & 15;
        const float2 ag2n = *(const float2*)(agbase + (size_t)an * DDIM + lane * 2);
        const float  gumn = gumbels[((size_t)an * NBATCH + gb_w) * NTASK + tau];
        const float  amkn = agent_mask[(size_t)gb_w * NAGENT + an];

        // ================= phase M: W-amortized matvec over all 8 g =========
        // upd[mj] partial over i in [iseg*64, iseg*64+64), weights from Wreg.
        float acc[G];
        #pragma unroll
        for (int g = 0; g < G; ++g) acc[g] = 0.f;
        #pragma unroll
        for (int c = 0; c < 16; ++c) {
            const int sb = c * 4 + iseg * 72;   // swz(iseg*64 + c*4)
            #pragma unroll
            for (int g = 0; g < G; ++g) {
                const float4 in4 = *(const float4*)(&scr[g][sb]);
                acc[g] = fmaf(in4.x, Wreg[c * 4 + 0], acc[g]);
                acc[g] = fmaf(in4.y, Wreg[c * 4 + 1], acc[g]);
                acc[g] = fmaf(in4.z, Wreg[c * 4 + 2], acc[g]);
                acc[g] = fmaf(in4.w, Wreg[c * 4 + 3], acc[g]);
            }
        }
        // reduce across the 4 adjacent iseg lanes
        #pragma unroll
        for (int g = 0; g < G; ++g) {
            float s = acc[g];
            s = s + __shfl_xor(s, 1);
            s = s + __shfl_xor(s, 2);
            acc[g] = s;
        }
        // epilogue: lane with iseg handles g in {2*iseg, 2*iseg+1}
        #pragma unroll
        for (int k = 0; k < 2; ++k) {
            const int g = iseg * 2 + k;
            const float u = acc[g] + bu;
            const int ts = tstar_s[g];
            const float addv = (u * hsel_s[g]) * agm_s[g];
            te[g][ts][mj] += addv;
        }
        __syncthreads();

        ag2 = ag2n; gum = gumn; amk = amkn;
    }
}

extern "C" void kernel_launch(void* const* d_in, const int* in_sizes, int n_in,
                              void* d_out, int out_size, void* d_ws, size_t ws_size,
                              hipStream_t stream) {
    const float*         task_embeds  = (const float*)d_in[0];
    const float*         task_nonag   = (const float*)d_in[1];
    const float*         agent_embeds = (const float*)d_in[2];
    const unsigned char* task_mask    = (const unsigned char*)d_in[3];
    const float*         agent_mask   = (const float*)d_in[4];
    const float*         gumbels      = (const float*)d_in[5];
    const float*         W_count      = (const float*)d_in[6];
    const float*         b_count      = (const float*)d_in[7];
    const float*         W_upd        = (const float*)d_in[8];
    const float*         b_upd        = (const float*)d_in[9];
    float* out = (float*)d_out;

    dim3 grid(NBATCH / G);
    dim3 block(NTHREADS);
    hipLaunchKernelGGL(alloc_policy_kernel, grid, block, 0, stream,
                       task_embeds, task_nonag, agent_embeds, task_mask,
                       agent_mask, gumbels, W_count, b_count, W_upd, b_upd, out);
}

// Round 5
// 125.850 us; speedup vs baseline: 2.8079x; 1.7434x over previous
//
#include <hip/hip_runtime.h>
#include <float.h>
#include <math.h>

#define NBATCH   4096
#define NAGENT   16
#define NTASK    16
#define DDIM     128
#define G        8      // batches per block (one per wave)
#define NTHREADS 512    // 8 waves
#define SSEG     20     // scr segment stride (16 data + 4 pad dwords) -> 2-way-free banks

// DPP quad_perm lane-xor (VALU pipe, not DS): xor1 = [1,0,3,2] = 0xB1, xor2 = [2,3,0,1] = 0x4E
template<int CTRL>
__device__ __forceinline__ float dppf(float x) {
    return __int_as_float(__builtin_amdgcn_update_dpp(
        0, __float_as_int(x), CTRL, 0xF, 0xF, true));
}
template<int CTRL>
__device__ __forceinline__ int dppi(int x) {
    return __builtin_amdgcn_update_dpp(0, x, CTRL, 0xF, 0xF, true);
}

__global__ __launch_bounds__(NTHREADS, 2)
void alloc_policy_kernel(const float* __restrict__ task_embeds,
                         const float* __restrict__ task_nonag,
                         const float* __restrict__ agent_embeds,
                         const unsigned char* __restrict__ task_mask,
                         const float* __restrict__ agent_mask,
                         const float* __restrict__ gumbels,
                         const float* __restrict__ W_count,
                         const float* __restrict__ b_count,
                         const float* __restrict__ W_upd,
                         const float* __restrict__ b_upd,
                         float* __restrict__ out)
{
    __shared__ __align__(16) float te[G][NTASK][DDIM];     // 64 KB
    __shared__ __align__(16) float scr[G][16 * SSEG];      // 10 KB, seg-strided relu input
    __shared__ __align__(16) float4 sdots4[G][NAGENT];     // 2 KB: (s0,s1,s2,_)
    __shared__ __align__(16) float4 upd4[G];               // (tstar-bits, hsel, agm, _)

    const int tid  = threadIdx.x;
    const int lane = tid & 63;
    const int w    = tid >> 6;            // wave id == batch slot g
    const int b0   = blockIdx.x * G;
    const int gb_w = b0 + w;

    const bool h0 = (lane & 1) != 0;
    const bool h1 = (lane & 2) != 0;
    const bool h2 = (lane & 4) != 0;
    const bool h3 = (lane & 8) != 0;

    // phase-M mapping: colgroup cg owns cols cg*4..cg*4+3; iseg owns i in [iseg*16, +16)
    const int cg   = tid >> 4;            // 0..31
    const int iseg = tid & 15;            // == lane & 15
    const float bu = b_upd[cg * 4 + (tid & 3)];   // bias for col = cg*4 + (lane&3)

    const float scalef = sqrtf(128.0f);

    // ---- W slice -> 64 VGPRs: Wq[c*4+di] = W_upd[iseg*16 + c*4 + di][cg*4 .. +3]
    float4 Wq[16];
    #pragma unroll
    for (int c = 0; c < 4; ++c)
        #pragma unroll
        for (int di = 0; di < 4; ++di)
            Wq[c * 4 + di] = *(const float4*)(W_upd +
                (size_t)(iseg * 16 + c * 4 + di) * DDIM + cg * 4);

    // ---- init te (block-wide coalesced copy)
    {
        const float4* src = (const float4*)(task_embeds + (size_t)b0 * NTASK * DDIM);
        float4* dst = (float4*)(&te[0][0][0]);
        #pragma unroll
        for (int k = 0; k < (G * NTASK * DDIM / 4) / NTHREADS; ++k)  // 8
            dst[k * NTHREADS + tid] = src[k * NTHREADS + tid];
    }

    // ---- init sdots4: s0=dot(ag,Wc0), s1=dot(ag,Wc1), s2=dot(ag,bc) per (g,a)
    {
        const int p = tid >> 2, q = tid & 3;
        const int g = p >> 4,  a = p & 15;
        const float* agp = agent_embeds + ((size_t)(b0 + g) * NAGENT + a) * DDIM + q * 32;
        float a0 = 0.f, a1 = 0.f, a2 = 0.f;
        #pragma unroll
        for (int c = 0; c < 8; ++c) {
            const float4 av = *(const float4*)(agp + c * 4);
            const float4 w0 = *(const float4*)(W_count + q * 32 + c * 4);
            const float4 w1 = *(const float4*)(W_count + DDIM + q * 32 + c * 4);
            const float4 bc = *(const float4*)(b_count + q * 32 + c * 4);
            a0 = fmaf(av.x, w0.x, a0); a0 = fmaf(av.y, w0.y, a0);
            a0 = fmaf(av.z, w0.z, a0); a0 = fmaf(av.w, w0.w, a0);
            a1 = fmaf(av.x, w1.x, a1); a1 = fmaf(av.y, w1.y, a1);
            a1 = fmaf(av.z, w1.z, a1); a1 = fmaf(av.w, w1.w, a1);
            a2 = fmaf(av.x, bc.x, a2); a2 = fmaf(av.y, bc.y, a2);
            a2 = fmaf(av.z, bc.z, a2); a2 = fmaf(av.w, bc.w, a2);
        }
        a0 += __shfl_xor(a0, 1); a0 += __shfl_xor(a0, 2);
        a1 += __shfl_xor(a1, 1); a1 += __shfl_xor(a1, 2);
        a2 += __shfl_xor(a2, 1); a2 += __shfl_xor(a2, 2);
        if (q == 0) sdots4[g][a] = make_float4(a0, a1, a2, 0.f);
    }

    // ---- per-lane task slot: tau = lane & 15 (x4 replicas over lane bits 4,5)
    const int tau = lane & 15;
    const float nn_my = task_nonag[gb_w * NTASK + tau];
    const unsigned char mask_my = task_mask[gb_w * NTASK + tau];
    float cc_my = 0.0f;

    // ---- prefetch step-0 per-step globals
    const float* agbase = agent_embeds + (size_t)gb_w * NAGENT * DDIM;
    float2 ag2 = *(const float2*)(agbase + lane * 2);
    float  gum = gumbels[(size_t)gb_w * NTASK + tau];            // a=0
    float  amk = agent_mask[(size_t)gb_w * NAGENT + 0];

    __syncthreads();

    for (int a = 0; a < NAGENT; ++a) {
        // ================= phase L (wave-private) =================
        float v[16];
        #pragma unroll
        for (int t = 0; t < 16; ++t) {
            const float2 t2 = *(const float2*)(&te[w][t][lane * 2]);
            v[t] = fmaf(ag2.y, t2.y, ag2.x * t2.x);
        }
        // packed butterfly, adjacent pairing: task-bit b <-> lane-bit b  => tau = lane&15
        float p8[8];
        #pragma unroll
        for (int m2 = 0; m2 < 8; ++m2) {
            const float lo = v[2 * m2], hi = v[2 * m2 + 1];
            const float send = h0 ? lo : hi;
            const float mine = h0 ? hi : lo;
            p8[m2] = mine + dppf<0xB1>(send);
        }
        float p4[4];
        #pragma unroll
        for (int m2 = 0; m2 < 4; ++m2) {
            const float lo = p8[2 * m2], hi = p8[2 * m2 + 1];
            const float send = h1 ? lo : hi;
            const float mine = h1 ? hi : lo;
            p4[m2] = mine + dppf<0x4E>(send);
        }
        float p2v[2];
        #pragma unroll
        for (int m2 = 0; m2 < 2; ++m2) {
            const float lo = p4[2 * m2], hi = p4[2 * m2 + 1];
            const float send = h2 ? lo : hi;
            const float mine = h2 ? hi : lo;
            p2v[m2] = mine + __shfl_xor(send, 4);
        }
        float p1;
        {
            const float lo = p2v[0], hi = p2v[1];
            const float send = h3 ? lo : hi;
            const float mine = h3 ? hi : lo;
            p1 = mine + __shfl_xor(send, 8);
        }
        p1 += __shfl_xor(p1, 16);
        p1 += __shfl_xor(p1, 32);   // all 64 lanes: full dot(ag, te[tau])

        const float4 sd = sdots4[w][a];
        const float dot_total = p1 + fmaf(nn_my, sd.x, fmaf(cc_my, sd.y, sd.z));
        float z = dot_total / scalef;
        if (mask_my) z = -FLT_MAX;
        z = z + gum;

        // softmax over 16 tasks = lane bits 0..3
        float mz = z;
        mz = fmaxf(mz, dppf<0xB1>(mz));
        mz = fmaxf(mz, dppf<0x4E>(mz));
        mz = fmaxf(mz, __shfl_xor(mz, 4));
        mz = fmaxf(mz, __shfl_xor(mz, 8));
        const float e = expf(z - mz);
        float ss = e;
        ss += dppf<0xB1>(ss);
        ss += dppf<0x4E>(ss);
        ss += __shfl_xor(ss, 4);
        ss += __shfl_xor(ss, 8);
        const float sft = e / ss;

        // argmax(soft), first-index tie-break: max of sft, then min tau among equals
        float mx = sft;
        mx = fmaxf(mx, dppf<0xB1>(mx));
        mx = fmaxf(mx, dppf<0x4E>(mx));
        mx = fmaxf(mx, __shfl_xor(mx, 4));
        mx = fmaxf(mx, __shfl_xor(mx, 8));
        int cand = (sft == mx) ? tau : NTASK;
        cand = min(cand, dppi<0xB1>(cand));
        cand = min(cand, dppi<0x4E>(cand));
        cand = min(cand, __shfl_xor(cand, 4));
        cand = min(cand, __shfl_xor(cand, 8));
        const int bi = cand;

        const float agm = 1.0f - amk;
        const float onehot = (tau == bi) ? 1.0f : 0.0f;
        const float hh = ((onehot - sft) + sft) * agm;   // exact 0 / exact agm

        if (lane < 16)
            out[((size_t)gb_w * NAGENT + a) * NTASK + tau] = hh;   // coalesced
        cc_my = cc_my + hh * 0.1f;
        if (lane < 16 && tau == bi)
            upd4[w] = make_float4(__int_as_float(bi), hh, agm, 0.f);

        // stage relu(concat(te[bi], ag)) into seg-strided scratch
        {
            const float2 tsel = *(const float2*)(&te[w][bi][lane * 2]);
            float2 r0, r1;
            r0.x = fmaxf(tsel.x, 0.f); r0.y = fmaxf(tsel.y, 0.f);
            r1.x = fmaxf(ag2.x, 0.f);  r1.y = fmaxf(ag2.y, 0.f);
            const int i0 = 2 * lane;          // te part
            const int i1 = 128 + 2 * lane;    // ag part
            *(float2*)(&scr[w][(i0 >> 4) * SSEG + (i0 & 15)]) = r0;
            *(float2*)(&scr[w][(i1 >> 4) * SSEG + (i1 & 15)]) = r1;
        }
        __syncthreads();

        // ---- prefetch next step's globals (hidden under phase M)
        const int an = (a + 1) & 15;
        const float2 ag2n = *(const float2*)(agbase + (size_t)an * DDIM + lane * 2);
        const float  gumn = gumbels[((size_t)an * NBATCH + gb_w) * NTASK + tau];
        const float  amkn = agent_mask[(size_t)gb_w * NAGENT + an];

        // ================= phase M: C=4 matvec, all 8 g =================
        float acc[32];   // j = g*4 + k
        #pragma unroll
        for (int j = 0; j < 32; ++j) acc[j] = 0.f;
        #pragma unroll
        for (int c = 0; c < 4; ++c) {
            const int sb = iseg * SSEG + c * 4;
            #pragma unroll
            for (int g = 0; g < 8; ++g) {
                const float4 in4 = *(const float4*)(&scr[g][sb]);
                {
                    const float4 wv = Wq[c * 4 + 0];
                    acc[g*4+0] = fmaf(in4.x, wv.x, acc[g*4+0]);
                    acc[g*4+1] = fmaf(in4.x, wv.y, acc[g*4+1]);
                    acc[g*4+2] = fmaf(in4.x, wv.z, acc[g*4+2]);
                    acc[g*4+3] = fmaf(in4.x, wv.w, acc[g*4+3]);
                }
                {
                    const float4 wv = Wq[c * 4 + 1];
                    acc[g*4+0] = fmaf(in4.y, wv.x, acc[g*4+0]);
                    acc[g*4+1] = fmaf(in4.y, wv.y, acc[g*4+1]);
                    acc[g*4+2] = fmaf(in4.y, wv.z, acc[g*4+2]);
                    acc[g*4+3] = fmaf(in4.y, wv.w, acc[g*4+3]);
                }
                {
                    const float4 wv = Wq[c * 4 + 2];
                    acc[g*4+0] = fmaf(in4.z, wv.x, acc[g*4+0]);
                    acc[g*4+1] = fmaf(in4.z, wv.y, acc[g*4+1]);
                    acc[g*4+2] = fmaf(in4.z, wv.z, acc[g*4+2]);
                    acc[g*4+3] = fmaf(in4.z, wv.w, acc[g*4+3]);
                }
                {
                    const float4 wv = Wq[c * 4 + 3];
                    acc[g*4+0] = fmaf(in4.w, wv.x, acc[g*4+0]);
                    acc[g*4+1] = fmaf(in4.w, wv.y, acc[g*4+1]);
                    acc[g*4+2] = fmaf(in4.w, wv.z, acc[g*4+2]);
                    acc[g*4+3] = fmaf(in4.w, wv.w, acc[g*4+3]);
                }
            }
        }
        // packed reduce over iseg (lane bits 0..3): 32 -> 2 values per lane
        float q16[16];
        #pragma unroll
        for (int m2 = 0; m2 < 16; ++m2) {
            const float lo = acc[2 * m2], hi = acc[2 * m2 + 1];
            const float send = h0 ? lo : hi;
            const float mine = h0 ? hi : lo;
            q16[m2] = mine + dppf<0xB1>(send);
        }
        float q8[8];
        #pragma unroll
        for (int m2 = 0; m2 < 8; ++m2) {
            const float lo = q16[2 * m2], hi = q16[2 * m2 + 1];
            const float send = h1 ? lo : hi;
            const float mine = h1 ? hi : lo;
            q8[m2] = mine + dppf<0x4E>(send);
        }
        float q4[4];
        #pragma unroll
        for (int m2 = 0; m2 < 4; ++m2) {
            const float lo = q8[2 * m2], hi = q8[2 * m2 + 1];
            const float send = h2 ? lo : hi;
            const float mine = h2 ? hi : lo;
            q4[m2] = mine + __shfl_xor(send, 4);
        }
        float q2[2];
        #pragma unroll
        for (int m2 = 0; m2 < 2; ++m2) {
            const float lo = q4[2 * m2], hi = q4[2 * m2 + 1];
            const float send = h3 ? lo : hi;
            const float mine = h3 ? hi : lo;
            q2[m2] = mine + __shfl_xor(send, 8);
        }
        // lane holds full sums for j1 = lane&15 (g=(lane&15)>>2, k=lane&3) and j2 = j1+16 (g+4)
        #pragma unroll
        for (int hgi = 0; hgi < 2; ++hgi) {
            const int g = ((lane & 15) >> 2) + hgi * 4;
            const float4 u4 = upd4[g];
            const int ts = __float_as_int(u4.x);
            const float u = q2[hgi] + bu;
            const float addv = (u * u4.y) * u4.z;
            te[g][ts][cg * 4 + (tid & 3)] += addv;
        }
        __syncthreads();

        ag2 = ag2n; gum = gumn; amk = amkn;
    }
}

extern "C" void kernel_launch(void* const* d_in, const int* in_sizes, int n_in,
                              void* d_out, int out_size, void* d_ws, size_t ws_size,
                              hipStream_t stream) {
    const float*         task_embeds  = (const float*)d_in[0];
    const float*         task_nonag   = (const float*)d_in[1];
    const float*         agent_embeds = (const float*)d_in[2];
    const unsigned char* task_mask    = (const unsigned char*)d_in[3];
    const float*         agent_mask   = (const float*)d_in[4];
    const float*         gumbels      = (const float*)d_in[5];
    const float*         W_count      = (const float*)d_in[6];
    const float*         b_count      = (const float*)d_in[7];
    const float*         W_upd        = (const float*)d_in[8];
    const float*         b_upd        = (const float*)d_in[9];
    float* out = (float*)d_out;

    dim3 grid(NBATCH / G);
    dim3 block(NTHREADS);
    hipLaunchKernelGGL(alloc_policy_kernel, grid, block, 0, stream,
                       task_embeds, task_nonag, agent_embeds, task_mask,
                       agent_mask, gumbels, W_count, b_count, W_upd, b_upd, out);
}